// Round 16
// baseline (90.252 us; speedup 1.0000x reference)
//
#include <hip/hip_runtime.h>
#include <stdint.h>

typedef __bf16 bf16x8 __attribute__((ext_vector_type(8)));
typedef float f32x4 __attribute__((ext_vector_type(4)));
typedef __attribute__((address_space(3))) uint32_t as3u32;
typedef const __attribute__((address_space(1))) uint32_t as1u32;

#define B_TOT 8192
#define DD 128
#define OUT_TOT 67108864UL
#define OUT_AVG 67117056UL

__device__ inline unsigned short f2bf(float x){
  union { float f; uint32_t u; } v; v.f = x;
  return (unsigned short)((v.u + 0x7fffu + ((v.u >> 16) & 1u)) >> 16);
}

// ------- phase 1+2 fused: gather/normalize/h/pos + lin1/leaky/lin2/sigmoid -----
// 1024 blocks x 512 threads; 8 samples/block (one per wave). W1 staged f32 in
// LDS once per block (XOR-swizzled vs the row-read pattern); h broadcast via
// 512B LDS; lane computes output cols {l, l+64}. Kills k_lin + one launch gap.
__global__ __launch_bounds__(512) void k_fl(const float* __restrict__ x1,
    const float* __restrict__ x2, const int* __restrict__ i1a, const int* __restrict__ i2a,
    const float* __restrict__ W1, const float* __restrict__ b1,
    const float* __restrict__ W2, const float* __restrict__ b2,
    unsigned short* __restrict__ f1b, unsigned short* __restrict__ f2b,
    float* __restrict__ posw, float* __restrict__ rTw, float* __restrict__ Tpart,
    float* __restrict__ out){
  __shared__ __align__(16) float W1S[16384];   // 64 KB
  __shared__ __align__(16) float hS[8][128];   // 4 KB
  __shared__ float TS[8];
  int tid = threadIdx.x;
  int gid = blockIdx.x * 512 + tid;
  if (gid < 8192) out[OUT_TOT + gid] = 0.f;    // zero tot accumulators
  // stage W1 -> W1S: LDS 4-float unit (j,u) holds global (j, u ^ (j&31))
  #pragma unroll
  for (int it = 0; it < 8; ++it){
    int c = tid + it * 512;                    // 4096 units
    int j = c >> 5, u = c & 31;
    int src = (j << 5) + (u ^ (j & 31));
    __builtin_amdgcn_global_load_lds((as1u32*)(W1 + src * 4),
                                     (as3u32*)(W1S + c * 4), 16, 0, 0);
  }
  int w = tid >> 6, l = tid & 63;
  int b = blockIdx.x * 8 + w;
  const float2* r1 = (const float2*)(x1 + (size_t)i1a[b] * DD);
  const float2* r2 = (const float2*)(x2 + (size_t)i2a[b] * DD);
  float2 v1 = r1[l], v2 = r2[l];
  float s1 = v1.x * v1.x + v1.y * v1.y;
  float s2 = v2.x * v2.x + v2.y * v2.y;
  #pragma unroll
  for (int o = 32; o; o >>= 1){ s1 += __shfl_xor(s1, o); s2 += __shfl_xor(s2, o); }
  float inv1 = 1.f / fmaxf(sqrtf(s1), 1e-12f);
  float inv2 = 1.f / fmaxf(sqrtf(s2), 1e-12f);
  float f1x = v1.x * inv1, f1y = v1.y * inv1;
  float f2x = v2.x * inv2, f2y = v2.y * inv2;
  float hx = f1x * f2x, hy = f1y * f2y;
  float ps = hx + hy;
  #pragma unroll
  for (int o = 32; o; o >>= 1) ps += __shfl_xor(ps, o);
  unsigned int u1 = (unsigned int)f2bf(f1x) | ((unsigned int)f2bf(f1y) << 16);
  unsigned int u2 = (unsigned int)f2bf(f2x) | ((unsigned int)f2bf(f2y) << 16);
  ((unsigned int*)f1b)[b * 64 + l] = u1;
  ((unsigned int*)f2b)[b * 64 + l] = u2;
  if (l == 0) posw[b] = ps;
  *(float2*)&hS[w][2 * l] = make_float2(hx, hy);   // h broadcast (f32, exact)
  asm volatile("s_waitcnt vmcnt(0)" ::: "memory");
  __syncthreads();                                  // W1S + hS ready
  // matvec: cols j1=l, j2=l+64; W1S read swizzle-corrected, bank-spread by l
  int j1 = l, j2 = l + 64, lm = l & 31;
  float z1 = 0.f, z2 = 0.f;
  #pragma unroll 8
  for (int u = 0; u < 32; ++u){
    f32x4 hq = *(const f32x4*)&hS[w][u * 4];        // broadcast
    f32x4 wa = *(const f32x4*)(W1S + j1 * 128 + ((u ^ lm) << 2));
    f32x4 wb = *(const f32x4*)(W1S + j2 * 128 + ((u ^ lm) << 2));
    z1 += hq.x * wa.x + hq.y * wa.y + hq.z * wa.z + hq.w * wa.w;
    z2 += hq.x * wb.x + hq.y * wb.y + hq.z * wb.z + hq.w * wb.w;
  }
  z1 += b1[j1]; z2 += b1[j2];
  z1 = z1 >= 0.f ? z1 : 0.2f * z1;                  // leaky_relu(0.2)
  z2 = z2 >= 0.f ? z2 : 0.2f * z2;
  float p = z1 * W2[j1] + z2 * W2[j2];
  #pragma unroll
  for (int o = 32; o; o >>= 1) p += __shfl_xor(p, o);
  float zz = p + b2[0];
  float sg = 1.f / (1.f + __expf(-zz));
  float T = 0.95f * (1.f - sg) + 0.05f;
  if (l == 0){ rTw[b] = 1.f / T; TS[w] = T; }
  __syncthreads();
  if (tid == 0){
    float t = 0.f;
    #pragma unroll
    for (int q = 0; q < 8; ++q) t += TS[q];
    Tpart[blockIdx.x] = t;
  }
}

// ------- staging helpers (XOR-swizzled, rule #21: pre-swizzled global src) ------
__device__ inline void stage_tile(const unsigned short* g, unsigned short* s){
  int tid = threadIdx.x;
  #pragma unroll
  for (int it = 0; it < 8; ++it){
    int c = tid + it * 256;          // 2048 chunks of 16B (128 rows x 16 chunks)
    int row = c >> 4, cc = c & 15;
    int src = (row << 4) + (cc ^ (row & 7));
    __builtin_amdgcn_global_load_lds((as1u32*)(g + src * 8),
                                     (as3u32*)(s + c * 8), 16, 0, 0);
  }
}
__device__ inline void stage_tile64(const unsigned short* g, unsigned short* s){
  int tid = threadIdx.x;
  #pragma unroll
  for (int it = 0; it < 4; ++it){
    int c = tid + it * 256;          // 1024 chunks (64 rows x 16 chunks)
    int row = c >> 4, cc = c & 15;
    int src = (row << 4) + (cc ^ (row & 7));
    __builtin_amdgcn_global_load_lds((as1u32*)(g + src * 8),
                                     (as3u32*)(s + c * 8), 16, 0, 0);
  }
}

// ------- phase 3 v3: tot GEMM with counted-vmcnt double-buffered B pipeline -----
__global__ __launch_bounds__(256, 2) void k_tot(const unsigned short* __restrict__ f1b,
    const unsigned short* __restrict__ f2b, const float* __restrict__ rTw,
    float* __restrict__ out){
  __shared__ __align__(16) unsigned short Abuf[16384];   // 32 KB
  __shared__ __align__(16) unsigned short Bbuf0[8192];   // 16 KB
  __shared__ __align__(16) unsigned short Bbuf1[8192];   // 16 KB
  __shared__ __align__(16) float rS[128];
  int s = (blockIdx.x & 7) * 64 + (blockIdx.x >> 3);     // XCD-chunked, bijective
  int rt = s & 63, ctg = s >> 6;
  int tid = threadIdx.x, w = tid >> 6, l = tid & 63;
  int wr = (w >> 1) * 64, wc = (w & 1) * 32;   // 2x2 wave grid over 128x64
  int lo = l & 15, hi = l >> 4;
  const unsigned short* Bg = f2b + (size_t)(ctg * 1024) * 128;  // 1024 cols
  stage_tile(f1b + (size_t)rt * 16384, Abuf);
  if (tid < 32)
    __builtin_amdgcn_global_load_lds((as1u32*)(rTw + rt * 128 + tid * 4),
                                     (as3u32*)(rS + tid * 4), 16, 0, 0);
  stage_tile64(Bg, Bbuf0);
  stage_tile64(Bg + 64 * 128, Bbuf1);
  asm volatile("s_waitcnt vmcnt(0)" ::: "memory");
  __builtin_amdgcn_s_barrier();
  bf16x8 af[4][4];                 // [kk][m] A fragments (64 VGPR)
  #pragma unroll
  for (int kk = 0; kk < 4; ++kk)
    #pragma unroll
    for (int m = 0; m < 4; ++m){
      int row = wr + m * 16 + lo;
      af[kk][m] = *(const bf16x8*)(Abuf + row * 128 + ((kk * 4 + hi) ^ (row & 7)) * 8);
    }
  float pacc[4][4] = {{0.f,0.f,0.f,0.f},{0.f,0.f,0.f,0.f},{0.f,0.f,0.f,0.f},{0.f,0.f,0.f,0.f}};
  unsigned short* ba = Bbuf0;
  unsigned short* bb = Bbuf1;
  #pragma unroll 1
  for (int i = 0; i < 16; ++i){
    if (i < 15) asm volatile("s_waitcnt vmcnt(4)" ::: "memory");
    else        asm volatile("s_waitcnt vmcnt(0)" ::: "memory");
    __builtin_amdgcn_s_barrier();            // buffer 'ba' ready for all waves
    f32x4 acc[4][2];
    f32x4 zero = {0.f,0.f,0.f,0.f};
    #pragma unroll
    for (int m = 0; m < 4; ++m){ acc[m][0] = zero; acc[m][1] = zero; }
    #pragma unroll
    for (int kk = 0; kk < 4; ++kk){
      bf16x8 bfv[2];
      #pragma unroll
      for (int n = 0; n < 2; ++n){
        int row = wc + n * 16 + lo;
        bfv[n] = *(const bf16x8*)(ba + row * 128 + ((kk * 4 + hi) ^ (row & 7)) * 8);
      }
      #pragma unroll
      for (int m = 0; m < 4; ++m){
        acc[m][0] = __builtin_amdgcn_mfma_f32_16x16x32_bf16(af[kk][m], bfv[0], acc[m][0], 0, 0, 0);
        acc[m][1] = __builtin_amdgcn_mfma_f32_16x16x32_bf16(af[kk][m], bfv[1], acc[m][1], 0, 0, 0);
      }
    }
    asm volatile("s_waitcnt lgkmcnt(0)" ::: "memory");
    __builtin_amdgcn_s_barrier();            // all waves done reading 'ba'
    if (i < 14) stage_tile64(Bg + (size_t)(i + 2) * 64 * 128, ba);  // depth-2 prefetch
    #pragma unroll
    for (int m = 0; m < 4; ++m)
      #pragma unroll
      for (int q = 0; q < 4; ++q){
        float r = rS[wr + m * 16 + hi * 4 + q];
        pacc[m][q] += __expf(acc[m][0][q] * r) + __expf(acc[m][1][q] * r);
      }
    unsigned short* t = ba; ba = bb; bb = t;
  }
  #pragma unroll
  for (int m = 0; m < 4; ++m)
    #pragma unroll
    for (int q = 0; q < 4; ++q){
      float p = pacc[m][q];
      p += __shfl_xor(p, 1); p += __shfl_xor(p, 2);
      p += __shfl_xor(p, 4); p += __shfl_xor(p, 8);
      if (lo == 0) atomicAdd(out + OUT_TOT + rt * 128 + wr + m * 16 + hi * 4 + q, p);
    }
}

// ------- phase 4: pos_rating writer + temp-mean finalize (block 0) --------------
__global__ __launch_bounds__(256) void k_pr(const float* __restrict__ posw,
    const float* __restrict__ rTw, const float* __restrict__ Tpart,
    float* __restrict__ out){
  int tid = threadIdx.x;
  if (blockIdx.x == 0){
    float t = Tpart[tid * 4] + Tpart[tid * 4 + 1] + Tpart[tid * 4 + 2] + Tpart[tid * 4 + 3];
    #pragma unroll
    for (int o = 32; o; o >>= 1) t += __shfl_xor(t, o);
    __shared__ float tsum[4];
    if ((tid & 63) == 0) tsum[tid >> 6] = t;
    __syncthreads();
    if (tid == 0) out[OUT_AVG] = (tsum[0] + tsum[1] + tsum[2] + tsum[3]) * (1.f / 8192.f);
  }
  int r0 = blockIdx.x * 4;
  f32x4 p[8];
  #pragma unroll
  for (int c = 0; c < 8; ++c) p[c] = *(const f32x4*)(posw + (c * 256 + tid) * 4);
  float4 rr4 = *(const float4*)(rTw + r0);
  float rr[4] = {rr4.x, rr4.y, rr4.z, rr4.w};
  #pragma unroll
  for (int r = 0; r < 4; ++r){
    float* ob = out + (size_t)(r0 + r) * B_TOT;
    #pragma unroll
    for (int c = 0; c < 8; ++c){
      f32x4 e;
      e.x = __expf(p[c].x * rr[r]); e.y = __expf(p[c].y * rr[r]);
      e.z = __expf(p[c].z * rr[r]); e.w = __expf(p[c].w * rr[r]);
      *(f32x4*)(ob + (c * 256 + tid) * 4) = e;
    }
  }
}

extern "C" void kernel_launch(void* const* d_in, const int* in_sizes, int n_in,
                              void* d_out, int out_size, void* d_ws, size_t ws_size,
                              hipStream_t stream){
  const float* x1 = (const float*)d_in[0];
  const float* x2 = (const float*)d_in[1];
  const int*   i1 = (const int*)d_in[2];
  const int*   i2 = (const int*)d_in[3];
  const float* W1 = (const float*)d_in[4];
  const float* b1 = (const float*)d_in[5];
  const float* W2 = (const float*)d_in[6];
  const float* b2 = (const float*)d_in[7];
  float* out = (float*)d_out;
  char* ws = (char*)d_ws;
  unsigned short* f1b  = (unsigned short*)(ws + 2097152);    // 2 MB
  unsigned short* f2b  = (unsigned short*)(ws + 4194304);    // 2 MB
  float* posw  = (float*)(ws + 6291456);                     // 32 KB
  float* rTw   = (float*)(ws + 6324224);                     // 32 KB
  float* Tpart = (float*)(ws + 6356992);                     // 4 KB

  hipLaunchKernelGGL(k_fl,  dim3(1024), dim3(512), 0, stream,
                     x1, x2, i1, i2, W1, b1, W2, b2, f1b, f2b, posw, rTw, Tpart, out);
  hipLaunchKernelGGL(k_tot, dim3(512),  dim3(256), 0, stream, f1b, f2b, rTw, out);
  hipLaunchKernelGGL(k_pr,  dim3(2048), dim3(256), 0, stream, posw, rTw, Tpart, out);
}